// Round 7
// baseline (328.682 us; speedup 1.0000x reference)
//
#include <hip/hip_runtime.h>
#include <hip/hip_bf16.h>
#include <stdint.h>

#define N_NODES 50000
#define N_EDGES 800000
#define IN_FEAT 256
#define OUT_FEAT 256
#define NUM_RELS 64
#define NUM_BASES 8
#define KTOT 2304           // Wt row stride: 8*256 + 256 self-loop
#define KAGG 2048           // A matrix K (bases only)
#define MP 50048            // 391 * 128 padded M
#define SCAN_BLKS 196

typedef __attribute__((ext_vector_type(8))) __bf16 bf16x8;
typedef __attribute__((ext_vector_type(4))) __bf16 bf16x4;
typedef __attribute__((ext_vector_type(4))) float f32x4;
typedef __attribute__((ext_vector_type(2))) float f32x2;

static __device__ __forceinline__ void gload_lds16(const void* g, void* l) {
  auto gp = (const __attribute__((address_space(1))) void*)(uintptr_t)g;
  auto lp = (__attribute__((address_space(3))) void*)(uint32_t)(uintptr_t)l;
  __builtin_amdgcn_global_load_lds(gp, lp, 16, 0, 0);
}

// ---------------- x -> bf16 ----------------
__global__ void k_prex(const float* __restrict__ x, __bf16* __restrict__ xb) {
  int i = blockIdx.x * 256 + threadIdx.x;
  const float4* xp = (const float4*)x;
  float4 u = xp[i * 2], v = xp[i * 2 + 1];
  bf16x8 o;
  o[0] = (__bf16)u.x; o[1] = (__bf16)u.y; o[2] = (__bf16)u.z; o[3] = (__bf16)u.w;
  o[4] = (__bf16)v.x; o[5] = (__bf16)v.y; o[6] = (__bf16)v.z; o[7] = (__bf16)v.w;
  *(bf16x8*)(xb + (size_t)i * 8) = o;
}

// ---------------- CSR build ----------------
__global__ void k_count(const int* __restrict__ dst, int* __restrict__ deg) {
  int e = blockIdx.x * 256 + threadIdx.x;
  atomicAdd(&deg[dst[e]], 1);
}

__global__ void k_scan1(const int* __restrict__ deg, int* __restrict__ offs,
                        int* __restrict__ bsum) {
  __shared__ int s[256];
  int t = threadIdx.x;
  int i = blockIdx.x * 256 + t;
  int v = (i < N_NODES) ? deg[i] : 0;
  s[t] = v;
  __syncthreads();
  for (int d = 1; d < 256; d <<= 1) {
    int y = (t >= d) ? s[t - d] : 0;
    __syncthreads();
    s[t] += y;
    __syncthreads();
  }
  if (i < N_NODES) offs[i] = s[t] - v;
  if (t == 255) bsum[blockIdx.x] = s[255];
}

// adds cross-block base (computed in-block from bsum) and inits fill
__global__ void k_scan3(int* __restrict__ offs, const int* __restrict__ bsum,
                        int* __restrict__ fill) {
  __shared__ int s[256];
  int t = threadIdx.x;
  s[t] = (t < SCAN_BLKS && t < blockIdx.x) ? bsum[t] : 0;
  __syncthreads();
  for (int d = 128; d; d >>= 1) {
    if (t < d) s[t] += s[t + d];
    __syncthreads();
  }
  int base = s[0];
  int i = blockIdx.x * 256 + t;
  if (i < N_NODES) {
    int o = offs[i] + base;
    offs[i] = o;
    fill[i] = o;
  }
}

// scatter packed edge records {src|ety<<16, norm} into CSR order
__global__ void k_scatter(const int* __restrict__ dst, const int* __restrict__ srcv,
                          const int* __restrict__ ety, const float* __restrict__ norm,
                          int* __restrict__ fill, uint2* __restrict__ erec) {
  int e = blockIdx.x * 256 + threadIdx.x;
  int pos = atomicAdd(&fill[dst[e]], 1);
  erec[pos] = make_uint2((unsigned)srcv[e] | ((unsigned)ety[e] << 16),
                         __float_as_uint(norm[e]));
}

// FMA micro-body shared by all unroll levels (compile-time indexing only)
#define AGG_BODY(RX, RY, XV)                                                  \
  do {                                                                        \
    int et_ = (RX) >> 16;                                                     \
    float nm_ = __uint_as_float(RY);                                          \
    f32x2 v0_ = {__uint_as_float((XV).x << 16) * nm_,                         \
                 __uint_as_float((XV).x & 0xffff0000u) * nm_};                 \
    f32x2 v1_ = {__uint_as_float((XV).y << 16) * nm_,                         \
                 __uint_as_float((XV).y & 0xffff0000u) * nm_};                 \
    f32x4 cl_ = *(const f32x4*)&wc[et_ * 8];                                  \
    f32x4 ch_ = *(const f32x4*)&wc[et_ * 8 + 4];                              \
    _Pragma("unroll") for (int b = 0; b < 4; ++b) {                           \
      acc[b][0] += v0_ * cl_[b];                                              \
      acc[b][1] += v1_ * cl_[b];                                              \
      acc[b + 4][0] += v0_ * ch_[b];                                          \
      acc[b + 4][1] += v1_ * ch_[b];                                          \
    }                                                                         \
  } while (0)

// ---------------- per-node aggregation: one wave per node ----------------
// lane owns 4 CONSECUTIVE features [lane*4 .. lane*4+3] x 8 bases.
// 8-deep unrolled gather: 8 independent x-row loads in flight per wave.
__global__ __launch_bounds__(256) void k_agg(
    const __bf16* __restrict__ xb, const float* __restrict__ w_comp,
    const int* __restrict__ offs, const int* __restrict__ fin,
    const uint2* __restrict__ erec, __bf16* __restrict__ A) {
  __shared__ float wc[NUM_RELS * NUM_BASES];   // 512 floats
  int t = threadIdx.x;
  wc[t] = w_comp[t];
  wc[t + 256] = w_comp[t + 256];
  __syncthreads();

  int wid = t >> 6, lane = t & 63;
  int node = blockIdx.x * 4 + wid;             // grid 12500 -> exactly 50000

  f32x2 acc[NUM_BASES][2];
#pragma unroll
  for (int b = 0; b < NUM_BASES; ++b) {
    acc[b][0] = f32x2{0.f, 0.f};
    acc[b][1] = f32x2{0.f, 0.f};
  }

  int i0 = offs[node];
  int cnt = fin[node] - i0;
  const uint2* rp = erec + i0;
  int lo4 = lane * 4;

  int i = 0;
  for (; i + 8 <= cnt; i += 8) {
    uint2 r[8];
#pragma unroll
    for (int j = 0; j < 8; ++j) r[j] = rp[i + j];
    uint2 xv[8];
#pragma unroll
    for (int j = 0; j < 8; ++j)
      xv[j] = *(const uint2*)(xb + (size_t)(r[j].x & 0xffff) * IN_FEAT + lo4);
#pragma unroll
    for (int j = 0; j < 8; ++j) AGG_BODY(r[j].x, r[j].y, xv[j]);
  }
  for (; i + 4 <= cnt; i += 4) {
    uint2 r[4];
#pragma unroll
    for (int j = 0; j < 4; ++j) r[j] = rp[i + j];
    uint2 xv[4];
#pragma unroll
    for (int j = 0; j < 4; ++j)
      xv[j] = *(const uint2*)(xb + (size_t)(r[j].x & 0xffff) * IN_FEAT + lo4);
#pragma unroll
    for (int j = 0; j < 4; ++j) AGG_BODY(r[j].x, r[j].y, xv[j]);
  }
  for (; i < cnt; ++i) {
    uint2 r = rp[i];
    uint2 xv = *(const uint2*)(xb + (size_t)(r.x & 0xffff) * IN_FEAT + lo4);
    AGG_BODY(r.x, r.y, xv);
  }

  __bf16* Ar = A + (size_t)node * KAGG + lo4;
#pragma unroll
  for (int b = 0; b < NUM_BASES; ++b) {
    bf16x4 o;
    o[0] = (__bf16)acc[b][0][0];
    o[1] = (__bf16)acc[b][0][1];
    o[2] = (__bf16)acc[b][1][0];
    o[3] = (__bf16)acc[b][1][1];
    *(bf16x4*)(Ar + b * 256) = o;
  }
}

// ---------------- weight prep: Wt[o][r] = Wcat[r][o] in bf16 ----------------
__global__ void k_prepw(const float* __restrict__ weight, const float* __restrict__ loop_w,
                        __bf16* __restrict__ Wt) {
  int o = blockIdx.x;
  int t = threadIdx.x;
#pragma unroll
  for (int c = 0; c < 9; ++c) {
    int r = c * 256 + t;
    float v = (r < 2048) ? weight[(size_t)r * 256 + o]
                         : loop_w[(size_t)(r - 2048) * 256 + o];
    Wt[(size_t)o * KTOT + r] = (__bf16)v;
  }
}

// ---------------- GEMM: out[M][256] = [A | xb] @ Wt^T + bias, relu ----------
// 128x256 tile, 4 waves (each 64 rows x 128 cols = 4x8 frags), BK=64 -> only
// 36 K-steps (halves per-step barrier/convergence overhead vs BK=32).
// 3 LDS buffers (144KB), depth-3 counted-vmcnt: 12 loads/stage, VMWAIT(24)
// in the main loop (never drains to 0). Row = 128B = 8 chunks of 16B;
// XOR-swizzle phys = logical ^ (row&7) (2-way bank aliasing = free).
__global__ __launch_bounds__(256, 1) void k_gemm(const __bf16* __restrict__ A,
                                                 const __bf16* __restrict__ xb,
                                                 const __bf16* __restrict__ Wt,
                                                 const float* __restrict__ bias,
                                                 float* __restrict__ out) {
  __shared__ __align__(16) __bf16 sA[3 * 128 * 64];   // 3 x 16KB
  __shared__ __align__(16) __bf16 sB[3 * 256 * 64];   // 3 x 32KB

  int t = threadIdx.x;
  int wid = t >> 6, lane = t & 63;
  int tm = blockIdx.x;
  int wr = wid >> 1, wc = wid & 1;
  int rfw = __builtin_amdgcn_readfirstlane(wid);

  f32x4 acc[4][8];
#pragma unroll
  for (int m = 0; m < 4; ++m)
#pragma unroll
    for (int n = 0; n < 8; ++n) acc[m][n] = f32x4{0.f, 0.f, 0.f, 0.f};

  int frow = lane & 15;
  int g = lane >> 4;                 // k-group 0..3
  int f7 = lane & 7;                 // row&7 for this lane's frag rows
  int kb0 = ((g ^ f7) << 4);         // k-half 0 swizzled byte offset
  int kb1 = (((4 + g) ^ f7) << 4);   // k-half 1

  // staging: chunk c = it*256 + t; row = c>>3 = it*32 + (t>>3); phys = t&7;
  // logical q = phys ^ (row&7) = (t&7) ^ ((t>>3)&7)  (same for all it)
  int qoff = ((t & 7) ^ ((t >> 3) & 7)) * 8;   // element offset in row
  const __bf16* gaP[4];
  const __bf16* gxP[4];
#pragma unroll
  for (int it = 0; it < 4; ++it) {
    int row = it * 32 + (t >> 3);
    gaP[it] = A + (size_t)(tm * 128 + row) * KAGG + qoff;
    gxP[it] = xb + (size_t)(tm * 128 + row) * IN_FEAT + qoff;
  }
  const __bf16* gbP[8];
#pragma unroll
  for (int it = 0; it < 8; ++it) {
    int row = it * 32 + (t >> 3);
    gbP[it] = Wt + (size_t)row * KTOT + qoff;
  }

#define VMWAIT(N) asm volatile("s_waitcnt vmcnt(" #N ")" ::: "memory")
#define BARRIER()                                   \
  do {                                              \
    asm volatile("" ::: "memory");                  \
    __builtin_amdgcn_s_barrier();                   \
    asm volatile("" ::: "memory");                  \
  } while (0)

#define STAGE(KT, BUF)                                                        \
  do {                                                                        \
    int k0_ = (KT) * 64;                                                      \
    char* bA_ = (char*)sA + (BUF) * 16384;                                    \
    char* bB_ = (char*)sB + (BUF) * 32768;                                    \
    if ((KT) < 32) {                                                          \
      _Pragma("unroll") for (int it = 0; it < 4; ++it)                        \
          gload_lds16(gaP[it] + k0_, bA_ + (it * 256 + rfw * 64) * 16);       \
    } else {                                                                  \
      int kx_ = k0_ - KAGG;                                                   \
      _Pragma("unroll") for (int it = 0; it < 4; ++it)                        \
          gload_lds16(gxP[it] + kx_, bA_ + (it * 256 + rfw * 64) * 16);       \
    }                                                                         \
    _Pragma("unroll") for (int it = 0; it < 8; ++it)                          \
        gload_lds16(gbP[it] + k0_, bB_ + (it * 256 + rfw * 64) * 16);         \
  } while (0)

#define COMPUTE(BUF)                                                          \
  do {                                                                        \
    const char* bA_ = (const char*)sA + (BUF) * 16384;                        \
    const char* bB_ = (const char*)sB + (BUF) * 32768;                        \
    {                                                                         \
      bf16x8 af[4], bfr[8];                                                   \
      _Pragma("unroll") for (int m = 0; m < 4; ++m)                           \
          af[m] = *(const bf16x8*)(bA_ + (wr * 64 + m * 16 + frow) * 128 + kb0);\
      _Pragma("unroll") for (int n = 0; n < 8; ++n)                           \
          bfr[n] = *(const bf16x8*)(bB_ + (wc * 128 + n * 16 + frow) * 128 + kb0);\
      _Pragma("unroll") for (int m = 0; m < 4; ++m)                           \
          _Pragma("unroll") for (int n = 0; n < 8; ++n)                       \
              acc[m][n] = __builtin_amdgcn_mfma_f32_16x16x32_bf16(            \
                  af[m], bfr[n], acc[m][n], 0, 0, 0);                         \
    }                                                                         \
    {                                                                         \
      bf16x8 af[4], bfr[8];                                                   \
      _Pragma("unroll") for (int m = 0; m < 4; ++m)                           \
          af[m] = *(const bf16x8*)(bA_ + (wr * 64 + m * 16 + frow) * 128 + kb1);\
      _Pragma("unroll") for (int n = 0; n < 8; ++n)                           \
          bfr[n] = *(const bf16x8*)(bB_ + (wc * 128 + n * 16 + frow) * 128 + kb1);\
      _Pragma("unroll") for (int m = 0; m < 4; ++m)                           \
          _Pragma("unroll") for (int n = 0; n < 8; ++n)                       \
              acc[m][n] = __builtin_amdgcn_mfma_f32_16x16x32_bf16(            \
                  af[m], bfr[n], acc[m][n], 0, 0, 0);                         \
    }                                                                         \
  } while (0)

  STAGE(0, 0);                        // 12 loads
  STAGE(1, 1);                        // 24 outstanding
  STAGE(2, 2);                        // 36 outstanding

#define STEP(KT, BUF)                                                         \
  do {                                                                        \
    VMWAIT(24);      /* oldest 12 (this BUF) retired; 24 stay in flight */    \
    BARRIER();       /* => ALL waves' loads for BUF retired */                \
    COMPUTE(BUF);                                                             \
    BARRIER();       /* all waves done reading BUF before overwrite */        \
    STAGE((KT) + 3, BUF);                                                     \
  } while (0)

  // 33 = 3*11 main steps (issue stages 3..35), then 3 drain steps
  for (int k3 = 0; k3 < 33; k3 += 3) {
    STEP(k3 + 0, 0);
    STEP(k3 + 1, 1);
    STEP(k3 + 2, 2);
  }
  VMWAIT(24); BARRIER(); COMPUTE(0);  // kt=33
  VMWAIT(12); BARRIER(); COMPUTE(1);  // kt=34
  VMWAIT(0);  BARRIER(); COMPUTE(2);  // kt=35
#undef STEP
#undef STAGE
#undef COMPUTE
#undef VMWAIT
#undef BARRIER

  // epilogue: C/D layout col = lane&15, row = (lane>>4)*4 + r
  int r0 = (lane >> 4) * 4;
  int c0 = lane & 15;
#pragma unroll
  for (int m = 0; m < 4; ++m) {
    int rowb = tm * 128 + wr * 64 + m * 16 + r0;
#pragma unroll
    for (int n = 0; n < 8; ++n) {
      int col = wc * 128 + n * 16 + c0;
      float bv = bias[col];
#pragma unroll
      for (int r = 0; r < 4; ++r) {
        int row = rowb + r;
        if (row < N_NODES) {
          float v = acc[m][n][r] + bv;
          out[(size_t)row * OUT_FEAT + col] = v > 0.f ? v : 0.f;
        }
      }
    }
  }
}

extern "C" void kernel_launch(void* const* d_in, const int* in_sizes, int n_in,
                              void* d_out, int out_size, void* d_ws, size_t ws_size,
                              hipStream_t stream) {
  const float* x      = (const float*)d_in[0];
  const int*   src    = (const int*)d_in[1];
  const int*   dst    = (const int*)d_in[2];
  const int*   ety    = (const int*)d_in[3];
  const float* norm   = (const float*)d_in[4];
  const float* weight = (const float*)d_in[5];
  const float* w_comp = (const float*)d_in[6];
  const float* h_bias = (const float*)d_in[7];
  const float* loop_w = (const float*)d_in[8];
  float* out = (float*)d_out;

  char* ws = (char*)d_ws;
  __bf16* A  = (__bf16*)ws;                                 // 205MB
  size_t off = (size_t)MP * KAGG * 2;
  __bf16* xb = (__bf16*)(ws + off);                         // 25.6MB
  off += (size_t)MP * IN_FEAT * 2;
  __bf16* Wt = (__bf16*)(ws + off);                         // 1.18MB
  off += (size_t)256 * KTOT * 2;
  uint2* erec = (uint2*)(ws + off);                         // 6.4MB
  off += (size_t)N_EDGES * 8;
  int* deg   = (int*)(ws + off);
  int* offs  = deg + N_NODES;
  int* fill  = offs + N_NODES;
  int* bsum  = fill + N_NODES;

  hipMemsetAsync(deg, 0, N_NODES * sizeof(int), stream);
  k_prex<<<(N_NODES * IN_FEAT / 8) / 256, 256, 0, stream>>>(x, xb);
  k_count<<<N_EDGES / 256, 256, 0, stream>>>(dst, deg);
  k_scan1<<<SCAN_BLKS, 256, 0, stream>>>(deg, offs, bsum);
  k_scan3<<<SCAN_BLKS, 256, 0, stream>>>(offs, bsum, fill);
  k_scatter<<<N_EDGES / 256, 256, 0, stream>>>(dst, src, ety, norm, fill, erec);
  k_agg<<<N_NODES / 4, 256, 0, stream>>>(xb, w_comp, offs, fill, erec, A);
  k_prepw<<<256, 256, 0, stream>>>(weight, loop_w, Wt);
  k_gemm<<<MP / 128, 256, 0, stream>>>(A, xb, Wt, h_bias, out);
}

// Round 8
// 294.279 us; speedup vs baseline: 1.1169x; 1.1169x over previous
//
#include <hip/hip_runtime.h>
#include <hip/hip_bf16.h>
#include <stdint.h>

#define N_NODES 50000
#define N_EDGES 800000
#define IN_FEAT 256
#define OUT_FEAT 256
#define NUM_RELS 64
#define NUM_BASES 8
#define KTOT 2304           // Wt row stride: 8*256 + 256 self-loop
#define KAGG 2048           // A matrix K (bases only)
#define MP 50176            // 196 * 256 padded M
#define NT 36               // K-tiles of 64
#define SCAN_BLKS 196

typedef __attribute__((ext_vector_type(8))) __bf16 bf16x8;
typedef __attribute__((ext_vector_type(4))) __bf16 bf16x4;
typedef __attribute__((ext_vector_type(4))) float f32x4;
typedef __attribute__((ext_vector_type(2))) float f32x2;

static __device__ __forceinline__ void gload_lds16(const void* g, void* l) {
  auto gp = (const __attribute__((address_space(1))) void*)(uintptr_t)g;
  auto lp = (__attribute__((address_space(3))) void*)(uint32_t)(uintptr_t)l;
  __builtin_amdgcn_global_load_lds(gp, lp, 16, 0, 0);
}

// ---------------- x -> bf16 ----------------
__global__ void k_prex(const float* __restrict__ x, __bf16* __restrict__ xb) {
  int i = blockIdx.x * 256 + threadIdx.x;
  const float4* xp = (const float4*)x;
  float4 u = xp[i * 2], v = xp[i * 2 + 1];
  bf16x8 o;
  o[0] = (__bf16)u.x; o[1] = (__bf16)u.y; o[2] = (__bf16)u.z; o[3] = (__bf16)u.w;
  o[4] = (__bf16)v.x; o[5] = (__bf16)v.y; o[6] = (__bf16)v.z; o[7] = (__bf16)v.w;
  *(bf16x8*)(xb + (size_t)i * 8) = o;
}

// ---------------- CSR build ----------------
__global__ void k_count(const int* __restrict__ dst, int* __restrict__ deg) {
  int e = blockIdx.x * 256 + threadIdx.x;
  atomicAdd(&deg[dst[e]], 1);
}

__global__ void k_scan1(const int* __restrict__ deg, int* __restrict__ offs,
                        int* __restrict__ bsum) {
  __shared__ int s[256];
  int t = threadIdx.x;
  int i = blockIdx.x * 256 + t;
  int v = (i < N_NODES) ? deg[i] : 0;
  s[t] = v;
  __syncthreads();
  for (int d = 1; d < 256; d <<= 1) {
    int y = (t >= d) ? s[t - d] : 0;
    __syncthreads();
    s[t] += y;
    __syncthreads();
  }
  if (i < N_NODES) offs[i] = s[t] - v;
  if (t == 255) bsum[blockIdx.x] = s[255];
}

// adds cross-block base (computed in-block from bsum) and inits fill
__global__ void k_scan3(int* __restrict__ offs, const int* __restrict__ bsum,
                        int* __restrict__ fill) {
  __shared__ int s[256];
  int t = threadIdx.x;
  s[t] = (t < SCAN_BLKS && t < blockIdx.x) ? bsum[t] : 0;
  __syncthreads();
  for (int d = 128; d; d >>= 1) {
    if (t < d) s[t] += s[t + d];
    __syncthreads();
  }
  int base = s[0];
  int i = blockIdx.x * 256 + t;
  if (i < N_NODES) {
    int o = offs[i] + base;
    offs[i] = o;
    fill[i] = o;
  }
}

// scatter packed edge records {src|ety<<16, norm} into CSR order
__global__ void k_scatter(const int* __restrict__ dst, const int* __restrict__ srcv,
                          const int* __restrict__ ety, const float* __restrict__ norm,
                          int* __restrict__ fill, uint2* __restrict__ erec) {
  int e = blockIdx.x * 256 + threadIdx.x;
  int pos = atomicAdd(&fill[dst[e]], 1);
  erec[pos] = make_uint2((unsigned)srcv[e] | ((unsigned)ety[e] << 16),
                         __float_as_uint(norm[e]));
}

// FMA micro-body shared by all unroll levels (compile-time indexing only)
#define AGG_BODY(RX, RY, XV)                                                  \
  do {                                                                        \
    int et_ = (RX) >> 16;                                                     \
    float nm_ = __uint_as_float(RY);                                          \
    f32x2 v0_ = {__uint_as_float((XV).x << 16) * nm_,                         \
                 __uint_as_float((XV).x & 0xffff0000u) * nm_};                 \
    f32x2 v1_ = {__uint_as_float((XV).y << 16) * nm_,                         \
                 __uint_as_float((XV).y & 0xffff0000u) * nm_};                 \
    f32x4 cl_ = *(const f32x4*)&wc[et_ * 8];                                  \
    f32x4 ch_ = *(const f32x4*)&wc[et_ * 8 + 4];                              \
    _Pragma("unroll") for (int b = 0; b < 4; ++b) {                           \
      acc[b][0] += v0_ * cl_[b];                                              \
      acc[b][1] += v1_ * cl_[b];                                              \
      acc[b + 4][0] += v0_ * ch_[b];                                          \
      acc[b + 4][1] += v1_ * ch_[b];                                          \
    }                                                                         \
  } while (0)

// ---------------- per-node aggregation: one wave per node ----------------
__global__ __launch_bounds__(256) void k_agg(
    const __bf16* __restrict__ xb, const float* __restrict__ w_comp,
    const int* __restrict__ offs, const int* __restrict__ fin,
    const uint2* __restrict__ erec, __bf16* __restrict__ A) {
  __shared__ float wc[NUM_RELS * NUM_BASES];   // 512 floats
  int t = threadIdx.x;
  wc[t] = w_comp[t];
  wc[t + 256] = w_comp[t + 256];
  __syncthreads();

  int wid = t >> 6, lane = t & 63;
  int node = blockIdx.x * 4 + wid;             // grid 12500 -> exactly 50000

  f32x2 acc[NUM_BASES][2];
#pragma unroll
  for (int b = 0; b < NUM_BASES; ++b) {
    acc[b][0] = f32x2{0.f, 0.f};
    acc[b][1] = f32x2{0.f, 0.f};
  }

  int i0 = offs[node];
  int cnt = fin[node] - i0;
  const uint2* rp = erec + i0;
  int lo4 = lane * 4;

  int i = 0;
  for (; i + 8 <= cnt; i += 8) {
    uint2 r[8];
#pragma unroll
    for (int j = 0; j < 8; ++j) r[j] = rp[i + j];
    uint2 xv[8];
#pragma unroll
    for (int j = 0; j < 8; ++j)
      xv[j] = *(const uint2*)(xb + (size_t)(r[j].x & 0xffff) * IN_FEAT + lo4);
#pragma unroll
    for (int j = 0; j < 8; ++j) AGG_BODY(r[j].x, r[j].y, xv[j]);
  }
  for (; i + 4 <= cnt; i += 4) {
    uint2 r[4];
#pragma unroll
    for (int j = 0; j < 4; ++j) r[j] = rp[i + j];
    uint2 xv[4];
#pragma unroll
    for (int j = 0; j < 4; ++j)
      xv[j] = *(const uint2*)(xb + (size_t)(r[j].x & 0xffff) * IN_FEAT + lo4);
#pragma unroll
    for (int j = 0; j < 4; ++j) AGG_BODY(r[j].x, r[j].y, xv[j]);
  }
  for (; i < cnt; ++i) {
    uint2 r = rp[i];
    uint2 xv = *(const uint2*)(xb + (size_t)(r.x & 0xffff) * IN_FEAT + lo4);
    AGG_BODY(r.x, r.y, xv);
  }

  __bf16* Ar = A + (size_t)node * KAGG + lo4;
#pragma unroll
  for (int b = 0; b < NUM_BASES; ++b) {
    bf16x4 o;
    o[0] = (__bf16)acc[b][0][0];
    o[1] = (__bf16)acc[b][0][1];
    o[2] = (__bf16)acc[b][1][0];
    o[3] = (__bf16)acc[b][1][1];
    *(bf16x4*)(Ar + b * 256) = o;
  }
}

// ---------------- weight prep: Wt[o][r] = Wcat[r][o] in bf16 ----------------
__global__ void k_prepw(const float* __restrict__ weight, const float* __restrict__ loop_w,
                        __bf16* __restrict__ Wt) {
  int o = blockIdx.x;
  int t = threadIdx.x;
#pragma unroll
  for (int c = 0; c < 9; ++c) {
    int r = c * 256 + t;
    float v = (r < 2048) ? weight[(size_t)r * 256 + o]
                         : loop_w[(size_t)(r - 2048) * 256 + o];
    Wt[(size_t)o * KTOT + r] = (__bf16)v;
  }
}

// ---------------- GEMM: 256x256 tile, 8 waves, 4-phase/K-tile pipeline -----
// m201-style schedule: per K-tile (BK=64) 4 phases, each
//   {frag ds_reads || stage ONE half-tile (2 gload_lds)} BAR prio1 16xMFMA prio0 BAR
// Stage stream 1 tile ahead at half granularity: P0->(t+1).A1, P1->(t+1).B0,
// P2->(t+1).B1, P3->(t+2).A0.  vmcnt(2) once per tile (after P3 MFMA) -- the
// load queue never drains in the main loop.  2 LDS buffers (128KB).
// Swizzle: phys chunk = logical ^ (row&7) on both stage-source and frag-read.
__global__ __launch_bounds__(512, 1) void k_gemm(const __bf16* __restrict__ A,
                                                 const __bf16* __restrict__ xb,
                                                 const __bf16* __restrict__ Wt,
                                                 const float* __restrict__ bias,
                                                 float* __restrict__ out) {
  __shared__ __align__(16) __bf16 sA[2 * 256 * 64];   // 2 x 32KB
  __shared__ __align__(16) __bf16 sB[2 * 256 * 64];   // 2 x 32KB

  int t = threadIdx.x;
  int wid = t >> 6, lane = t & 63;
  int tm = blockIdx.x;
  int wr = wid >> 2;                 // A row-half 0..1 (128 rows)
  int wcol = wid & 3;                // B col-group 0..3 (64 cols)
  int rfw = __builtin_amdgcn_readfirstlane(wid);

  f32x4 acc[8][4];
#pragma unroll
  for (int m = 0; m < 8; ++m)
#pragma unroll
    for (int n = 0; n < 4; ++n) acc[m][n] = f32x4{0.f, 0.f, 0.f, 0.f};

  int frow = lane & 15;
  int g = lane >> 4;
  int f7 = frow & 7;
  int kb0 = ((g ^ f7) << 4);         // k-half 0 swizzled chunk byte
  int kb1 = (((4 + g) ^ f7) << 4);   // k-half 1

  // staging sources: chunk c = it*512 + t; row-in-half = it*64 + (t>>3);
  // phys = t&7; logical q = phys ^ (row&7)
  int rh = t >> 3;
  int qoff = ((t & 7) ^ (rh & 7)) * 8;
  const __bf16* gA[2][2];            // [half][it]
  const __bf16* gX[2][2];
  const __bf16* gB[2][2];
#pragma unroll
  for (int h = 0; h < 2; ++h)
#pragma unroll
    for (int it = 0; it < 2; ++it) {
      int row = h * 128 + it * 64 + rh;
      gA[h][it] = A + (size_t)(tm * 256 + row) * KAGG + qoff;
      gX[h][it] = xb + (size_t)(tm * 256 + row) * IN_FEAT + qoff;
      gB[h][it] = Wt + (size_t)row * KTOT + qoff;
    }

  bf16x8 af[4][2];                   // current m-sub A frags [mf][kh]
  bf16x8 bh0[2][2], bh1[2][2];       // B frags n-half 0 / 1 [nf][kh]

#define VMWAIT(N) asm volatile("s_waitcnt vmcnt(" #N ")" ::: "memory")
#define BAR()                                       \
  do {                                              \
    asm volatile("" ::: "memory");                  \
    __builtin_amdgcn_s_barrier();                   \
    asm volatile("" ::: "memory");                  \
  } while (0)
#define PRIO(N) __builtin_amdgcn_s_setprio(N)

#define STAGE_A(H, U, BUF)                                                    \
  do {                                                                        \
    char* d_ = (char*)sA + (BUF) * 32768 + (H) * 16384 + rfw * 1024;          \
    if ((U) < 32) {                                                           \
      int ko_ = (U) * 64;                                                     \
      gload_lds16(gA[H][0] + ko_, d_);                                        \
      gload_lds16(gA[H][1] + ko_, d_ + 8192);                                 \
    } else {                                                                  \
      int ko_ = ((U) - 32) * 64;                                              \
      gload_lds16(gX[H][0] + ko_, d_);                                        \
      gload_lds16(gX[H][1] + ko_, d_ + 8192);                                 \
    }                                                                         \
  } while (0)

#define STAGE_B(H, U, BUF)                                                    \
  do {                                                                        \
    char* d_ = (char*)sB + (BUF) * 32768 + (H) * 16384 + rfw * 1024;          \
    int ko_ = (U) * 64;                                                       \
    gload_lds16(gB[H][0] + ko_, d_);                                          \
    gload_lds16(gB[H][1] + ko_, d_ + 8192);                                   \
  } while (0)

#define READ_A(BUF, MS)                                                       \
  do {                                                                        \
    const char* b_ = (const char*)sA + (BUF) * 32768;                         \
    _Pragma("unroll") for (int mf = 0; mf < 4; ++mf) {                        \
      int r_ = wr * 128 + (MS) * 64 + mf * 16 + frow;                         \
      af[mf][0] = *(const bf16x8*)(b_ + r_ * 128 + kb0);                      \
      af[mf][1] = *(const bf16x8*)(b_ + r_ * 128 + kb1);                      \
    }                                                                         \
  } while (0)

#define READ_B(BUF, NH, DST)                                                  \
  do {                                                                        \
    const char* b_ = (const char*)sB + (BUF) * 32768;                         \
    _Pragma("unroll") for (int nf = 0; nf < 2; ++nf) {                        \
      int r_ = wcol * 64 + ((NH) * 2 + nf) * 16 + frow;                       \
      DST[nf][0] = *(const bf16x8*)(b_ + r_ * 128 + kb0);                     \
      DST[nf][1] = *(const bf16x8*)(b_ + r_ * 128 + kb1);                     \
    }                                                                         \
  } while (0)

#define MFMA16(MS, NH, BS)                                                    \
  do {                                                                        \
    _Pragma("unroll") for (int mf = 0; mf < 4; ++mf)                          \
    _Pragma("unroll") for (int nf = 0; nf < 2; ++nf) {                        \
      acc[(MS) * 4 + mf][(NH) * 2 + nf] =                                     \
          __builtin_amdgcn_mfma_f32_16x16x32_bf16(                            \
              af[mf][0], BS[nf][0], acc[(MS) * 4 + mf][(NH) * 2 + nf], 0, 0, 0);\
      acc[(MS) * 4 + mf][(NH) * 2 + nf] =                                     \
          __builtin_amdgcn_mfma_f32_16x16x32_bf16(                            \
              af[mf][1], BS[nf][1], acc[(MS) * 4 + mf][(NH) * 2 + nf], 0, 0, 0);\
    }                                                                         \
  } while (0)

  // prologue: tile0 fully + tile1.A0 (issue order matters for vmcnt)
  STAGE_A(0, 0, 0);
  STAGE_A(1, 0, 0);
  STAGE_B(0, 0, 0);
  STAGE_B(1, 0, 0);
  STAGE_A(0, 1, 1);
  VMWAIT(2);                          // tile0's 4 halves retired
  BAR();

  for (int kt = 0; kt < NT; ++kt) {
    int cb = kt & 1, nb = cb ^ 1;
    int u1 = (kt + 1 < NT) ? kt + 1 : NT - 1;
    int u2 = (kt + 2 < NT) ? kt + 2 : NT - 1;
    // P0: quadrant (m0, n0)
    READ_A(cb, 0);
    READ_B(cb, 0, bh0);
    STAGE_A(1, u1, nb);
    BAR(); PRIO(1); MFMA16(0, 0, bh0); PRIO(0); BAR();
    // P1: (m0, n1)
    READ_B(cb, 1, bh1);
    STAGE_B(0, u1, nb);
    BAR(); PRIO(1); MFMA16(0, 1, bh1); PRIO(0); BAR();
    // P2: (m1, n0)
    READ_A(cb, 1);
    STAGE_B(1, u1, nb);
    BAR(); PRIO(1); MFMA16(1, 0, bh0); PRIO(0); BAR();
    // P3: (m1, n1)
    STAGE_A(0, u2, cb);
    BAR(); PRIO(1); MFMA16(1, 1, bh1); PRIO(0);
    VMWAIT(2);                        // tile kt+1 retired; (kt+2).A0 in flight
    BAR();
  }
#undef STAGE_A
#undef STAGE_B
#undef READ_A
#undef READ_B
#undef MFMA16
#undef VMWAIT
#undef BAR
#undef PRIO

  // epilogue: C/D layout col = lane&15, row = (lane>>4)*4 + r
  int r0 = (lane >> 4) * 4;
  int c0 = lane & 15;
#pragma unroll
  for (int m = 0; m < 8; ++m) {
    int rowb = tm * 256 + wr * 128 + m * 16 + r0;
#pragma unroll
    for (int n = 0; n < 4; ++n) {
      int col = wcol * 64 + n * 16 + c0;
      float bv = bias[col];
#pragma unroll
      for (int r = 0; r < 4; ++r) {
        int row = rowb + r;
        if (row < N_NODES) {
          float v = acc[m][n][r] + bv;
          out[(size_t)row * OUT_FEAT + col] = v > 0.f ? v : 0.f;
        }
      }
    }
  }
}

extern "C" void kernel_launch(void* const* d_in, const int* in_sizes, int n_in,
                              void* d_out, int out_size, void* d_ws, size_t ws_size,
                              hipStream_t stream) {
  const float* x      = (const float*)d_in[0];
  const int*   src    = (const int*)d_in[1];
  const int*   dst    = (const int*)d_in[2];
  const int*   ety    = (const int*)d_in[3];
  const float* norm   = (const float*)d_in[4];
  const float* weight = (const float*)d_in[5];
  const float* w_comp = (const float*)d_in[6];
  const float* h_bias = (const float*)d_in[7];
  const float* loop_w = (const float*)d_in[8];
  float* out = (float*)d_out;

  char* ws = (char*)d_ws;
  __bf16* A  = (__bf16*)ws;                                 // 205.5MB
  size_t off = (size_t)MP * KAGG * 2;
  __bf16* xb = (__bf16*)(ws + off);                         // 25.7MB
  off += (size_t)MP * IN_FEAT * 2;
  __bf16* Wt = (__bf16*)(ws + off);                         // 1.18MB
  off += (size_t)256 * KTOT * 2;
  uint2* erec = (uint2*)(ws + off);                         // 6.4MB
  off += (size_t)N_EDGES * 8;
  int* deg   = (int*)(ws + off);
  int* offs  = deg + N_NODES;
  int* fill  = offs + N_NODES;
  int* bsum  = fill + N_NODES;

  hipMemsetAsync(deg, 0, N_NODES * sizeof(int), stream);
  k_prex<<<(N_NODES * IN_FEAT / 8) / 256, 256, 0, stream>>>(x, xb);
  k_count<<<N_EDGES / 256, 256, 0, stream>>>(dst, deg);
  k_scan1<<<SCAN_BLKS, 256, 0, stream>>>(deg, offs, bsum);
  k_scan3<<<SCAN_BLKS, 256, 0, stream>>>(offs, bsum, fill);
  k_scatter<<<N_EDGES / 256, 256, 0, stream>>>(dst, src, ety, norm, fill, erec);
  k_agg<<<N_NODES / 4, 256, 0, stream>>>(xb, w_comp, offs, fill, erec, A);
  k_prepw<<<256, 256, 0, stream>>>(weight, loop_w, Wt);
  k_gemm<<<MP / 256, 512, 0, stream>>>(A, xb, Wt, h_bias, out);
}